// Round 1
// baseline (118.684 us; speedup 1.0000x reference)
//
#include <hip/hip_runtime.h>
#include <math.h>

#define NC   24
#define NPTS 1536
#define NH   40
#define FEPS 1e-8f

// Bool-mask format detection: rows begin with >=768 'true' entries, so the
// first 32-bit word disambiguates: uint8 -> 0x01010101, int32 -> 1, f32 -> 1.0f
__device__ __forceinline__ int mask_fmt(const void* m) {
    int w = ((const int*)m)[0];
    if (w == 1) return 1;            // int32
    if (w == 0x3f800000) return 2;   // float32
    return 0;                        // uint8 / numpy bool
}
__device__ __forceinline__ bool mask_at(const void* m, int idx, int fmt) {
    if (fmt == 1) return ((const int*)m)[idx] != 0;
    if (fmt == 2) return ((const float*)m)[idx] != 0.0f;
    return ((const unsigned char*)m)[idx] != 0;
}

__global__ __launch_bounds__(256)
void csep_kernel(const float* __restrict__ pts, const float* __restrict__ hulls,
                 const float* __restrict__ med, const float* __restrict__ ang,
                 const float* __restrict__ trans, const void* __restrict__ cmask,
                 const void* __restrict__ hmask, float* __restrict__ out)
{
    const int tid = threadIdx.x;
    const int i = blockIdx.y;                  // point cluster
    const int z = blockIdx.z;
    const int j = z + (z >= i ? 1 : 0);        // hull cluster, j != i

    __shared__ float  s_vx[NH], s_vy[NH];
    __shared__ float4 s_edges[NH];
    __shared__ int    s_hullok;
    __shared__ float  s_part[4];

    const int cfmt = mask_fmt(cmask);

    // penalty terms, added exactly once per launch
    if (blockIdx.x == 0 && i == 0 && z == 0 && tid == 0) {
        float pen = 0.f;
        for (int c = 0; c < NC; ++c) {
            float tx = trans[2*c], ty = trans[2*c+1], a = ang[c];
            pen += 0.1f * (tx*tx + ty*ty) + 1.0f * (a*a);
        }
        atomicAdd(out, pen);
    }

    // stage transformed hull-j vertices into LDS
    if (tid < NH) {
        float sj, cj;
        __sincosf(ang[j], &sj, &cj);
        float mx = med[2*j], my = med[2*j+1];
        float tx = trans[2*j], ty = trans[2*j+1];
        float x = hulls[(j*NH + tid)*2 + 0];
        float y = hulls[(j*NH + tid)*2 + 1];
        float cx = x - mx, cy = y - my;
        s_vx[tid] = cx*cj - cy*sj + mx + tx;
        s_vy[tid] = cx*sj + cy*cj + my + ty;
    }
    if (tid == 0) {
        int hfmt = mask_fmt(hmask);
        int cnt = 0;
        for (int h = 0; h < NH; ++h) cnt += mask_at(hmask, j*NH + h, hfmt) ? 1 : 0;
        s_hullok = (cnt >= 3);
    }
    __syncthreads();

    // edges: p1 = v[h], p2 = v[(h+1) % H]
    if (tid < NH) {
        int hn = (tid + 1 == NH) ? 0 : tid + 1;
        float ex = s_vx[hn] - s_vx[tid];
        float ey = s_vy[hn] - s_vy[tid];
        float el = sqrtf(ex*ex + ey*ey);
        float inv = (el > 1e-6f) ? 1.0f / (el + FEPS) : 0.0f;  // inv==0 marks invalid
        float c0 = ex*s_vy[tid] - ey*s_vx[tid];
        s_edges[tid] = make_float4(ex, ey, c0, inv);
    }
    __syncthreads();

    if (!s_hullok) return;   // uniform across block

    // transform this thread's point with cluster-i params
    const int n = blockIdx.x * 256 + tid;
    const bool pm = mask_at(cmask, i*NPTS + n, cfmt);
    float si, ci;
    __sincosf(ang[i], &si, &ci);
    const float mx = med[2*i], my = med[2*i+1];
    const float tx = trans[2*i], ty = trans[2*i+1];
    const float x = pts[(i*NPTS + n)*2 + 0];
    const float y = pts[(i*NPTS + n)*2 + 1];
    const float cx = x - mx, cy = y - my;
    const float px = cx*ci - cy*si + mx + tx;
    const float py = cx*si + cy*ci + my + ty;

    bool allpos = true, allneg = true;
    float minabs = INFINITY;
#pragma unroll
    for (int h = 0; h < NH; ++h) {
        float4 e = s_edges[h];
        // cross = ex*py - ey*px - c0 ; signed = cross / (elen+eps)
        float cross = fmaf(e.x, py, -fmaf(e.y, px, e.z));
        float sgn = cross * e.w;             // invalid edge: e.w==0 -> sgn==0, passes both tests
        allpos = allpos && (sgn >= -FEPS);
        allneg = allneg && (sgn <=  FEPS);
        float cand = (e.w > 0.f) ? fabsf(sgn) : INFINITY;
        minabs = fminf(minabs, cand);
    }

    float viol = 0.f;
    if (pm && (allpos || allneg))
        viol = 1.0f / (1.0f + __expf(-minabs));   // sigmoid(min_abs); inf -> 1 matches ref

    // block reduction: wave shuffle then LDS across the 4 waves
#pragma unroll
    for (int off = 32; off > 0; off >>= 1)
        viol += __shfl_down(viol, off, 64);
    const int lane = tid & 63, wid = tid >> 6;
    if (lane == 0) s_part[wid] = viol;
    __syncthreads();
    if (tid == 0) atomicAdd(out, s_part[0] + s_part[1] + s_part[2] + s_part[3]);
}

extern "C" void kernel_launch(void* const* d_in, const int* in_sizes, int n_in,
                              void* d_out, int out_size, void* d_ws, size_t ws_size,
                              hipStream_t stream) {
    const float* pts   = (const float*)d_in[0];   // (C,N,2)
    const float* hulls = (const float*)d_in[1];   // (C,H,2)
    const float* med   = (const float*)d_in[2];   // (C,2)
    const float* ang   = (const float*)d_in[3];   // (C,)
    const float* trans = (const float*)d_in[4];   // (C,2)
    const void*  cmask = d_in[5];                 // (C,N) bool
    const void*  hmask = d_in[6];                 // (C,H) bool
    float* out = (float*)d_out;

    hipMemsetAsync(out, 0, sizeof(float), stream);
    dim3 grid(NPTS / 256, NC, NC - 1);
    csep_kernel<<<grid, dim3(256, 1, 1), 0, stream>>>(pts, hulls, med, ang, trans,
                                                      cmask, hmask, out);
}

// Round 2
// 89.797 us; speedup vs baseline: 1.3217x; 1.3217x over previous
//
#include <hip/hip_runtime.h>
#include <math.h>

#define NC    24
#define NPTS  1536
#define NH    40
#define FEPS  1e-8f
#define GROUPS 4
#define JPG    6   // hulls per group (NC / GROUPS)

// Bool-mask format detection: rows begin with >=768 'true' entries, so the
// first 32-bit word disambiguates: uint8 -> 0x01010101, int32 -> 1, f32 -> 1.0f
__device__ __forceinline__ int mask_fmt(const void* m) {
    int w = ((const int*)m)[0];
    if (w == 1) return 1;            // int32
    if (w == 0x3f800000) return 2;   // float32
    return 0;                        // uint8 / numpy bool
}
__device__ __forceinline__ bool mask_at(const void* m, int idx, int fmt) {
    if (fmt == 1) return ((const int*)m)[idx] != 0;
    if (fmt == 2) return ((const float*)m)[idx] != 0.0f;
    return ((const unsigned char*)m)[idx] != 0;
}

// ---------- Kernel A: one block. Transform all hulls -> edges in ws, hull_ok
// flags, and the translation/rotation penalty. ----------
__global__ __launch_bounds__(1024)
void prep_kernel(const float* __restrict__ hulls, const float* __restrict__ med,
                 const float* __restrict__ ang, const float* __restrict__ trans,
                 const void* __restrict__ hmask,
                 float4* __restrict__ edges, int* __restrict__ hok,
                 float* __restrict__ out)
{
    const int tid = threadIdx.x;
    if (tid < NC * NH) {
        const int j = tid / NH, h = tid % NH;
        float sj, cj;
        __sincosf(ang[j], &sj, &cj);
        const float mx = med[2*j], my = med[2*j+1];
        const float tx = trans[2*j], ty = trans[2*j+1];
        const int hn = (h + 1 == NH) ? 0 : h + 1;
        const float x1 = hulls[(j*NH + h )*2], y1 = hulls[(j*NH + h )*2 + 1];
        const float x2 = hulls[(j*NH + hn)*2], y2 = hulls[(j*NH + hn)*2 + 1];
        const float cx1 = x1 - mx, cy1 = y1 - my;
        const float p1x = cx1*cj - cy1*sj + mx + tx;
        const float p1y = cx1*sj + cy1*cj + my + ty;
        const float cx2 = x2 - mx, cy2 = y2 - my;
        const float p2x = cx2*cj - cy2*sj + mx + tx;
        const float p2y = cx2*sj + cy2*cj + my + ty;
        const float ex = p2x - p1x, ey = p2y - p1y;
        const float el = sqrtf(ex*ex + ey*ey);
        const float inv = (el > 1e-6f) ? 1.0f / (el + FEPS) : 0.0f; // 0 marks invalid
        const float c0 = ex*p1y - ey*p1x;
        edges[tid] = make_float4(ex, ey, c0, inv);
    } else if (tid < NC * NH + NC) {
        const int j = tid - NC * NH;
        const int hfmt = mask_fmt(hmask);
        int cnt = 0;
        for (int h = 0; h < NH; ++h) cnt += mask_at(hmask, j*NH + h, hfmt) ? 1 : 0;
        hok[j] = (cnt >= 3) ? 1 : 0;
    } else if (tid == 1023) {
        float pen = 0.f;
        for (int c = 0; c < NC; ++c) {
            const float tx = trans[2*c], ty = trans[2*c+1], a = ang[c];
            pen += 0.1f * (tx*tx + ty*ty) + 1.0f * (a*a);
        }
        atomicAdd(out, pen);
    }
}

// ---------- Kernel B: grid (N/256, C, GROUPS). Each thread transforms its
// point once and sweeps JPG hulls x NH edges from LDS. ----------
__global__ __launch_bounds__(256)
void eval_kernel(const float* __restrict__ pts, const float* __restrict__ med,
                 const float* __restrict__ ang, const float* __restrict__ trans,
                 const void* __restrict__ cmask,
                 const float4* __restrict__ edges, const int* __restrict__ hok,
                 float* __restrict__ out)
{
    const int tid = threadIdx.x;
    const int i = blockIdx.y;       // point cluster
    const int z = blockIdx.z;       // hull group

    __shared__ float4 s_e[JPG * NH];
    __shared__ int    s_ok[JPG];
    __shared__ float  s_part[4];

    if (tid < JPG * NH) s_e[tid] = edges[z * JPG * NH + tid];
    if (tid < JPG)      s_ok[tid] = hok[z * JPG + tid];
    __syncthreads();

    // transform this thread's point with cluster-i params
    const int n = blockIdx.x * 256 + tid;
    const int cfmt = mask_fmt(cmask);
    const bool pm = mask_at(cmask, i*NPTS + n, cfmt);
    float si, ci;
    __sincosf(ang[i], &si, &ci);
    const float mx = med[2*i], my = med[2*i+1];
    const float tx = trans[2*i], ty = trans[2*i+1];
    const float x = pts[(i*NPTS + n)*2 + 0];
    const float y = pts[(i*NPTS + n)*2 + 1];
    const float cx = x - mx, cy = y - my;
    const float px = cx*ci - cy*si + mx + tx;
    const float py = cx*si + cy*ci + my + ty;

    float acc = 0.f;
    for (int g = 0; g < JPG; ++g) {
        const int j = z * JPG + g;
        if (j == i || !s_ok[g]) continue;   // uniform across block
        bool allpos = true, allneg = true;
        float minabs = INFINITY;
#pragma unroll
        for (int h = 0; h < NH; ++h) {
            const float4 e = s_e[g*NH + h];
            // cross = ex*py - ey*px - c0 ; signed = cross / (elen+eps)
            const float cross = fmaf(e.x, py, -fmaf(e.y, px, e.z));
            const float sgn = cross * e.w;   // invalid edge: e.w==0 -> passes both tests
            allpos = allpos && (sgn >= -FEPS);
            allneg = allneg && (sgn <=  FEPS);
            minabs = fminf(minabs, (e.w > 0.f) ? fabsf(sgn) : INFINITY);
        }
        if (allpos || allneg)
            acc += 1.0f / (1.0f + __expf(-minabs));  // sigmoid; inf -> 1 matches ref
    }
    if (!pm) acc = 0.f;

    // block reduction: wave shuffle then LDS across the 4 waves
#pragma unroll
    for (int off = 32; off > 0; off >>= 1)
        acc += __shfl_down(acc, off, 64);
    const int lane = tid & 63, wid = tid >> 6;
    if (lane == 0) s_part[wid] = acc;
    __syncthreads();
    if (tid == 0) atomicAdd(out, s_part[0] + s_part[1] + s_part[2] + s_part[3]);
}

extern "C" void kernel_launch(void* const* d_in, const int* in_sizes, int n_in,
                              void* d_out, int out_size, void* d_ws, size_t ws_size,
                              hipStream_t stream) {
    const float* pts   = (const float*)d_in[0];   // (C,N,2)
    const float* hulls = (const float*)d_in[1];   // (C,H,2)
    const float* med   = (const float*)d_in[2];   // (C,2)
    const float* ang   = (const float*)d_in[3];   // (C,)
    const float* trans = (const float*)d_in[4];   // (C,2)
    const void*  cmask = d_in[5];                 // (C,N) bool
    const void*  hmask = d_in[6];                 // (C,H) bool
    float* out = (float*)d_out;

    float4* edges = (float4*)d_ws;                        // NC*NH float4 = 15360 B
    int*    hok   = (int*)((char*)d_ws + NC*NH*sizeof(float4)); // NC ints

    hipMemsetAsync(out, 0, sizeof(float), stream);
    prep_kernel<<<1, 1024, 0, stream>>>(hulls, med, ang, trans, hmask, edges, hok, out);
    dim3 grid(NPTS / 256, NC, GROUPS);
    eval_kernel<<<grid, dim3(256, 1, 1), 0, stream>>>(pts, med, ang, trans, cmask,
                                                      edges, hok, out);
}